// Round 2
// baseline (229.114 us; speedup 1.0000x reference)
//
#include <hip/hip_runtime.h>

// Problem constants (from reference): stimuli [4,32,304,608,1] fp32, eye [4,32,2,3] fp32
#define BH 304
#define BW 608
#define BHW (BH * BW)   // 184832 = 722 * 256
#define NFRAMES 128

__global__ __launch_bounds__(256) void warp_bilinear_kernel(
    const float* __restrict__ stimuli,
    const float* __restrict__ eye,
    float* __restrict__ out)
{
    const int n = blockIdx.y;                       // frame index (wave-uniform)
    const int p = blockIdx.x * 256 + threadIdx.x;   // pixel index within frame

    // Affine coefficients: uniform across block -> scalar loads
    const float* aff = eye + n * 6;
    const float a00 = aff[0], a01 = aff[1], a02 = aff[2];
    const float a10 = aff[3], a11 = aff[4], a12 = aff[5];

    const int px = p % BW;
    const int py = p / BW;

    // grid coords in [-1, 1] (linspace)
    const float xx = -1.0f + 2.0f * (float)px / (float)(BW - 1);
    const float yy = -1.0f + 2.0f * (float)py / (float)(BH - 1);

    // affine transform -> source pixel coords
    const float tx = a00 * xx + a01 * yy + a02;
    const float ty = a10 * xx + a11 * yy + a12;
    const float x = (tx + 1.0f) * (0.5f * (float)BW);
    const float y = (ty + 1.0f) * (0.5f * (float)BH);

    int x0 = (int)floorf(x);
    int y0 = (int)floorf(y);
    int x1 = x0 + 1;
    int y1 = y0 + 1;
    x0 = min(max(x0, 0), BW - 1);
    x1 = min(max(x1, 0), BW - 1);
    y0 = min(max(y0, 0), BH - 1);
    y1 = min(max(y1, 0), BH - 1);

    const float* __restrict__ img = stimuli + (size_t)n * BHW;
    const float Ia = img[y0 * BW + x0];
    const float Ib = img[y1 * BW + x0];
    const float Ic = img[y0 * BW + x1];
    const float Id = img[y1 * BW + x1];

    const float x0f = (float)x0, x1f = (float)x1;
    const float y0f = (float)y0, y1f = (float)y1;
    const float wa = (x1f - x) * (y1f - y);
    const float wb = (x1f - x) * (y - y0f);
    const float wc = (x - x0f) * (y1f - y);
    const float wd = (x - x0f) * (y - y0f);

    out[(size_t)n * BHW + p] = wa * Ia + wb * Ib + wc * Ic + wd * Id;
}

extern "C" void kernel_launch(void* const* d_in, const int* in_sizes, int n_in,
                              void* d_out, int out_size, void* d_ws, size_t ws_size,
                              hipStream_t stream) {
    const float* stimuli = (const float*)d_in[0];  // 4*32*304*608*1 fp32
    const float* eye     = (const float*)d_in[1];  // 4*32*2*3 fp32
    float* out = (float*)d_out;

    dim3 grid(BHW / 256, NFRAMES);  // 722 x 128
    dim3 block(256);
    warp_bilinear_kernel<<<grid, block, 0, stream>>>(stimuli, eye, out);
}